// Round 15
// baseline (457.983 us; speedup 1.0000x reference)
//
#include <hip/hip_runtime.h>
#include <stdint.h>

// VectorQuantizer (eval fwd): inputs [64,64,32,32] f32 NCHW, embedding [1024,64] f32.
// Outputs concatenated: quantized [64,64,32,32] f32, loss scalar, perplexity scalar.
//
// Round-15 = round-14 + 4 rows/thread (RPB 256).
//  r14 per-CU pipe budget: pk 27.3us + LDS 27us + scalar feed ~parity -> 127us
//  wall at 58% busy. 4 rows/thread: LDS halves to 13.7us/CU (threads/CU halve),
//  one s_load_dwordx16 feeds 64 cyc of pk (feed-rich 1.5-2x), compare/init
//  overhead halves. Cost: 1 block/CU (grid 256), 2 waves/SIMD -- ILP replaces TLP.
//  Registers: acc[8][4]+xr[4][8] ~ 140 live -> NO __launch_bounds__ minimum
//  (default 256-VGPR budget; r9/r10: a declared cap silently spills. Grid caps
//  residency at 8 waves/CU anyway). All array indices compile-time constants.
//  - 512-thread blocks, 8 waves x 128 codes, 256 rows/block, grid 256.
//  - e/e2 via readfirstlane-uniform addresses -> s_load scalar pipe; ev staged
//    in 64B runs -> s_load_dwordx16 (r13-proven).
// dist = ||e||^2 - 2 x.e; 2-chain pk summation per code (r13/r14-proven, absmax 0.0).

#define K_CODES 1024
#define DIM 64
#define HW 1024          // 32*32
#define N_ROWS 65536
#define OUT_ELEMS 4194304
#define XSTR 68          // x row stride in dwords
#define RPB 256          // rows per block

// ws layout (float indices)
#define WS_E2   0        // 1024 f32: ||e_k||^2
#define WS_CNT  1024     // 1024 u32: counts
#define WS_LOSS 2048     // 1 f32

__global__ void vq_init(const float* __restrict__ emb, float* __restrict__ ws) {
    const int k = blockIdx.x * blockDim.x + threadIdx.x;  // 1024 threads total
    if (k < K_CODES) {
        const float4* e4 = reinterpret_cast<const float4*>(emb + k * DIM);
        float s = 0.f;
#pragma unroll
        for (int i = 0; i < DIM / 4; ++i) {
            float4 v = e4[i];
            s += v.x * v.x + v.y * v.y + v.z * v.z + v.w * v.w;
        }
        ws[WS_E2 + k] = s;
        reinterpret_cast<unsigned int*>(ws)[WS_CNT + k] = 0u;
    }
    if (blockIdx.x == 0 && threadIdx.x == 0) ws[WS_LOSS] = 0.f;
}

__global__ void vq_main(
    const float* __restrict__ in, const float* __restrict__ emb,
    float* __restrict__ out, float* __restrict__ ws)
{
    __shared__ __align__(16) float xs[RPB * XSTR];   // 69632 B
    __shared__ float bwd[8][RPB];
    __shared__ int   bwk[8][RPB];
    __shared__ int   fk[RPB];
    __shared__ float lred[8];

    const int t = threadIdx.x;
    const int w = t >> 6;        // wave id 0..7
    const int l = t & 63;
    const int w_u = __builtin_amdgcn_readfirstlane(w);   // SGPR wave id

    const int row0 = blockIdx.x * RPB;
    const int b = row0 >> 10, hw0 = row0 & 1023;   // 256 | 1024 -> rows stay in one b
    const float* xin = in + b * (DIM * HW) + hw0;

    // ---- stage x tile: thread (w,l): rows l+64r, channels [8w, 8w+8) ----
#pragma unroll
    for (int rr = 0; rr < 4; ++rr) {
        const int r = rr * 64 + l;
#pragma unroll
        for (int cc = 0; cc < 8; ++cc) {
            const int c = w * 8 + cc;
            xs[r * XSTR + c] = xin[c * HW + r];   // lanes l consecutive -> coalesced
        }
    }
    __syncthreads();

    // ---- argmin over this wave's 128 codes for 4 rows (k0 wave-uniform) ----
    const float* e2 = ws + WS_E2;
    float best[4] = {3.4e38f, 3.4e38f, 3.4e38f, 3.4e38f};
    int   bkr[4]  = {0, 0, 0, 0};
    const int k0 = w_u * 128;

    for (int kg = 0; kg < 128; kg += 8) {
        float2 acc[8][4];                        // [code][row]
#pragma unroll
        for (int c = 0; c < 8; ++c)
#pragma unroll
            for (int r = 0; r < 4; ++r) acc[c][r] = make_float2(0.f, 0.f);

#pragma unroll
        for (int ch = 0; ch < 4; ++ch) {        // 4 chunks of 16 dims
            float2 xr[4][8];                     // [row][pair]
#pragma unroll
            for (int r = 0; r < 4; ++r) {
                const float* xp = xs + (r * 64 + l) * XSTR + ch * 16;
                *(float4*)(&xr[r][0]) = *(const float4*)(xp);
                *(float4*)(&xr[r][2]) = *(const float4*)(xp + 4);
                *(float4*)(&xr[r][4]) = *(const float4*)(xp + 8);
                *(float4*)(&xr[r][6]) = *(const float4*)(xp + 12);
            }
#pragma unroll
            for (int c = 0; c < 8; ++c) {
                // 64B run of e -> s_load_dwordx16; feeds 64 pk (4 rows)
                const float2* ep = (const float2*)(emb + (k0 + kg + c) * DIM + ch * 16);
                float2 ev[8];
#pragma unroll
                for (int j = 0; j < 8; ++j) ev[j] = ep[j];
#pragma unroll
                for (int j = 0; j < 8; ++j) {
#pragma unroll
                    for (int r = 0; r < 4; ++r) {
                        asm("v_pk_fma_f32 %0, %1, %2, %0"
                            : "+v"(acc[c][r]) : "s"(ev[j]), "v"(xr[r][j]));
                    }
                }
            }
        }
#pragma unroll
        for (int c = 0; c < 8; ++c) {
            const int k = k0 + kg + c;
            const float e2v = e2[k];
#pragma unroll
            for (int r = 0; r < 4; ++r) {
                const float d = fmaf(-2.f, acc[c][r].x + acc[c][r].y, e2v);
                if (d < best[r]) { best[r] = d; bkr[r] = k; }   // strict <
            }
        }
    }

#pragma unroll
    for (int r = 0; r < 4; ++r) {
        bwd[w][r * 64 + l] = best[r];
        bwk[w][r * 64 + l] = bkr[r];
    }
    __syncthreads();

    // ---- lex-merge across the 8 waves (k-ranges ascending) ----
    if (t < RPB) {
        float bb = bwd[0][t]; int bk = bwk[0][t];
#pragma unroll
        for (int s = 1; s < 8; ++s) {
            const float d = bwd[s][t]; const int k = bwk[s][t];
            if (d < bb || (d == bb && k < bk)) { bb = d; bk = k; }
        }
        fk[t] = bk;
        atomicAdd(reinterpret_cast<unsigned int*>(ws) + WS_CNT + bk, 1u);
    }
    __syncthreads();

    // ---- fused epilogue: thread (w,l): 4 rows, channels [8w, 8w+8) ----
    float* outp = out + b * (DIM * HW) + hw0;
    float lsum = 0.f;
#pragma unroll
    for (int rr = 0; rr < 4; ++rr) {
        const int r = rr * 64 + l;
        const int bk = fk[r];
        const float4* eq = reinterpret_cast<const float4*>(emb + bk * DIM + w * 8);
        const float* xrow = xs + r * XSTR;
#pragma unroll
        for (int i = 0; i < 2; ++i) {
            const float4 q = eq[i];
            const int c0 = w * 8 + 4 * i;
            const float4 xq = *(const float4*)(xrow + c0);  // aligned
            const float d0 = q.x - xq.x, d1 = q.y - xq.y;
            const float d2 = q.z - xq.z, d3 = q.w - xq.w;
            lsum += d0 * d0 + d1 * d1 + d2 * d2 + d3 * d3;
            outp[(c0 + 0) * HW + r] = xq.x + d0;   // STE: x + (q - x)
            outp[(c0 + 1) * HW + r] = xq.y + d1;
            outp[(c0 + 2) * HW + r] = xq.z + d2;
            outp[(c0 + 3) * HW + r] = xq.w + d3;
        }
    }

#pragma unroll
    for (int off = 32; off; off >>= 1) lsum += __shfl_down(lsum, off, 64);
    if (l == 0) lred[w] = lsum;
    __syncthreads();
    if (t == 0) {
        float s = 0.f;
#pragma unroll
        for (int i = 0; i < 8; ++i) s += lred[i];
        atomicAdd(ws + WS_LOSS, s);
    }
}

__global__ void vq_final(float* __restrict__ out, const float* __restrict__ ws) {
    __shared__ float red[16];
    const int t = threadIdx.x;  // 1024 threads
    const unsigned int* counts = reinterpret_cast<const unsigned int*>(ws) + WS_CNT;
    float p = (float)counts[t] * (1.0f / 65536.f);
    float v = p * logf(p + 1e-10f);
#pragma unroll
    for (int off = 32; off; off >>= 1) v += __shfl_down(v, off, 64);
    if ((t & 63) == 0) red[t >> 6] = v;
    __syncthreads();
    if (t == 0) {
        float s = 0.f;
#pragma unroll
        for (int i = 0; i < 16; ++i) s += red[i];
        out[OUT_ELEMS]     = 0.25f * (1.0f / (float)OUT_ELEMS) * ws[WS_LOSS];
        out[OUT_ELEMS + 1] = expf(-s);
    }
}

extern "C" void kernel_launch(void* const* d_in, const int* in_sizes, int n_in,
                              void* d_out, int out_size, void* d_ws, size_t ws_size,
                              hipStream_t stream) {
    const float* in  = (const float*)d_in[0];
    const float* emb = (const float*)d_in[1];
    float* out = (float*)d_out;
    float* ws  = (float*)d_ws;

    vq_init<<<4, 256, 0, stream>>>(emb, ws);
    vq_main<<<N_ROWS / RPB, 512, 0, stream>>>(in, emb, out, ws);
    vq_final<<<1, 1024, 0, stream>>>(out, ws);
}

// Round 16
// 179.009 us; speedup vs baseline: 2.5584x; 2.5584x over previous
//
#include <hip/hip_runtime.h>
#include <stdint.h>

// VectorQuantizer (eval fwd): inputs [64,64,32,32] f32 NCHW, embedding [1024,64] f32.
// Outputs concatenated: quantized [64,64,32,32] f32, loss scalar, perplexity scalar.
//
// Round-16 = round-15 + __launch_bounds__(512, 1).
//  r15 spilled: with NO bounds the compiler chose a 64-VGPR target for the
//  512-thread block (occupancy heuristic), but acc[8][4]+xr[4][8] ~ 140 live
//  -> scratch (WRITE 18->34 MB, 478us). Budget law measured across r9/r11/r14:
//  budget = 2048/(8*arg2) VGPRs -> (512,1) = 256: fits with slack. LDS 87.5KB
//  already caps residency at 1 block/CU, so the declared cap costs nothing.
//  - 512-thread blocks, 8 waves x 128 codes, 256 rows/block (4 rows/thread),
//    grid 256 -> 1 block/CU -> 2 waves/SIMD; ILP: 4 pk chains/j-step,
//    ~5 dwordx16 e-runs prefetchable (320cyc consumption vs ~200cyc latency).
//  - e/e2 via readfirstlane-uniform addresses -> s_load scalar pipe; ev staged
//    in 64B runs -> s_load_dwordx16 (r13-proven).
// dist = ||e||^2 - 2 x.e; 2-chain pk summation per code (r13/r14-proven, absmax 0.0).

#define K_CODES 1024
#define DIM 64
#define HW 1024          // 32*32
#define N_ROWS 65536
#define OUT_ELEMS 4194304
#define XSTR 68          // x row stride in dwords
#define RPB 256          // rows per block

// ws layout (float indices)
#define WS_E2   0        // 1024 f32: ||e_k||^2
#define WS_CNT  1024     // 1024 u32: counts
#define WS_LOSS 2048     // 1 f32

__global__ void vq_init(const float* __restrict__ emb, float* __restrict__ ws) {
    const int k = blockIdx.x * blockDim.x + threadIdx.x;  // 1024 threads total
    if (k < K_CODES) {
        const float4* e4 = reinterpret_cast<const float4*>(emb + k * DIM);
        float s = 0.f;
#pragma unroll
        for (int i = 0; i < DIM / 4; ++i) {
            float4 v = e4[i];
            s += v.x * v.x + v.y * v.y + v.z * v.z + v.w * v.w;
        }
        ws[WS_E2 + k] = s;
        reinterpret_cast<unsigned int*>(ws)[WS_CNT + k] = 0u;
    }
    if (blockIdx.x == 0 && threadIdx.x == 0) ws[WS_LOSS] = 0.f;
}

__global__ __launch_bounds__(512, 1) void vq_main(
    const float* __restrict__ in, const float* __restrict__ emb,
    float* __restrict__ out, float* __restrict__ ws)
{
    __shared__ __align__(16) float xs[RPB * XSTR];   // 69632 B
    __shared__ float bwd[8][RPB];
    __shared__ int   bwk[8][RPB];
    __shared__ int   fk[RPB];
    __shared__ float lred[8];

    const int t = threadIdx.x;
    const int w = t >> 6;        // wave id 0..7
    const int l = t & 63;
    const int w_u = __builtin_amdgcn_readfirstlane(w);   // SGPR wave id

    const int row0 = blockIdx.x * RPB;
    const int b = row0 >> 10, hw0 = row0 & 1023;   // 256 | 1024 -> rows stay in one b
    const float* xin = in + b * (DIM * HW) + hw0;

    // ---- stage x tile: thread (w,l): rows l+64r, channels [8w, 8w+8) ----
#pragma unroll
    for (int rr = 0; rr < 4; ++rr) {
        const int r = rr * 64 + l;
#pragma unroll
        for (int cc = 0; cc < 8; ++cc) {
            const int c = w * 8 + cc;
            xs[r * XSTR + c] = xin[c * HW + r];   // lanes l consecutive -> coalesced
        }
    }
    __syncthreads();

    // ---- argmin over this wave's 128 codes for 4 rows (k0 wave-uniform) ----
    const float* e2 = ws + WS_E2;
    float best[4] = {3.4e38f, 3.4e38f, 3.4e38f, 3.4e38f};
    int   bkr[4]  = {0, 0, 0, 0};
    const int k0 = w_u * 128;

    for (int kg = 0; kg < 128; kg += 8) {
        float2 acc[8][4];                        // [code][row]
#pragma unroll
        for (int c = 0; c < 8; ++c)
#pragma unroll
            for (int r = 0; r < 4; ++r) acc[c][r] = make_float2(0.f, 0.f);

#pragma unroll
        for (int ch = 0; ch < 4; ++ch) {        // 4 chunks of 16 dims
            float2 xr[4][8];                     // [row][pair]
#pragma unroll
            for (int r = 0; r < 4; ++r) {
                const float* xp = xs + (r * 64 + l) * XSTR + ch * 16;
                *(float4*)(&xr[r][0]) = *(const float4*)(xp);
                *(float4*)(&xr[r][2]) = *(const float4*)(xp + 4);
                *(float4*)(&xr[r][4]) = *(const float4*)(xp + 8);
                *(float4*)(&xr[r][6]) = *(const float4*)(xp + 12);
            }
#pragma unroll
            for (int c = 0; c < 8; ++c) {
                // 64B run of e -> s_load_dwordx16; feeds 64 pk (4 rows)
                const float2* ep = (const float2*)(emb + (k0 + kg + c) * DIM + ch * 16);
                float2 ev[8];
#pragma unroll
                for (int j = 0; j < 8; ++j) ev[j] = ep[j];
#pragma unroll
                for (int j = 0; j < 8; ++j) {
#pragma unroll
                    for (int r = 0; r < 4; ++r) {
                        asm("v_pk_fma_f32 %0, %1, %2, %0"
                            : "+v"(acc[c][r]) : "s"(ev[j]), "v"(xr[r][j]));
                    }
                }
            }
        }
#pragma unroll
        for (int c = 0; c < 8; ++c) {
            const int k = k0 + kg + c;
            const float e2v = e2[k];
#pragma unroll
            for (int r = 0; r < 4; ++r) {
                const float d = fmaf(-2.f, acc[c][r].x + acc[c][r].y, e2v);
                if (d < best[r]) { best[r] = d; bkr[r] = k; }   // strict <
            }
        }
    }

#pragma unroll
    for (int r = 0; r < 4; ++r) {
        bwd[w][r * 64 + l] = best[r];
        bwk[w][r * 64 + l] = bkr[r];
    }
    __syncthreads();

    // ---- lex-merge across the 8 waves (k-ranges ascending) ----
    if (t < RPB) {
        float bb = bwd[0][t]; int bk = bwk[0][t];
#pragma unroll
        for (int s = 1; s < 8; ++s) {
            const float d = bwd[s][t]; const int k = bwk[s][t];
            if (d < bb || (d == bb && k < bk)) { bb = d; bk = k; }
        }
        fk[t] = bk;
        atomicAdd(reinterpret_cast<unsigned int*>(ws) + WS_CNT + bk, 1u);
    }
    __syncthreads();

    // ---- fused epilogue: thread (w,l): 4 rows, channels [8w, 8w+8) ----
    float* outp = out + b * (DIM * HW) + hw0;
    float lsum = 0.f;
#pragma unroll
    for (int rr = 0; rr < 4; ++rr) {
        const int r = rr * 64 + l;
        const int bk = fk[r];
        const float4* eq = reinterpret_cast<const float4*>(emb + bk * DIM + w * 8);
        const float* xrow = xs + r * XSTR;
#pragma unroll
        for (int i = 0; i < 2; ++i) {
            const float4 q = eq[i];
            const int c0 = w * 8 + 4 * i;
            const float4 xq = *(const float4*)(xrow + c0);  // aligned
            const float d0 = q.x - xq.x, d1 = q.y - xq.y;
            const float d2 = q.z - xq.z, d3 = q.w - xq.w;
            lsum += d0 * d0 + d1 * d1 + d2 * d2 + d3 * d3;
            outp[(c0 + 0) * HW + r] = xq.x + d0;   // STE: x + (q - x)
            outp[(c0 + 1) * HW + r] = xq.y + d1;
            outp[(c0 + 2) * HW + r] = xq.z + d2;
            outp[(c0 + 3) * HW + r] = xq.w + d3;
        }
    }

#pragma unroll
    for (int off = 32; off; off >>= 1) lsum += __shfl_down(lsum, off, 64);
    if (l == 0) lred[w] = lsum;
    __syncthreads();
    if (t == 0) {
        float s = 0.f;
#pragma unroll
        for (int i = 0; i < 8; ++i) s += lred[i];
        atomicAdd(ws + WS_LOSS, s);
    }
}

__global__ void vq_final(float* __restrict__ out, const float* __restrict__ ws) {
    __shared__ float red[16];
    const int t = threadIdx.x;  // 1024 threads
    const unsigned int* counts = reinterpret_cast<const unsigned int*>(ws) + WS_CNT;
    float p = (float)counts[t] * (1.0f / 65536.f);
    float v = p * logf(p + 1e-10f);
#pragma unroll
    for (int off = 32; off; off >>= 1) v += __shfl_down(v, off, 64);
    if ((t & 63) == 0) red[t >> 6] = v;
    __syncthreads();
    if (t == 0) {
        float s = 0.f;
#pragma unroll
        for (int i = 0; i < 16; ++i) s += red[i];
        out[OUT_ELEMS]     = 0.25f * (1.0f / (float)OUT_ELEMS) * ws[WS_LOSS];
        out[OUT_ELEMS + 1] = expf(-s);
    }
}

extern "C" void kernel_launch(void* const* d_in, const int* in_sizes, int n_in,
                              void* d_out, int out_size, void* d_ws, size_t ws_size,
                              hipStream_t stream) {
    const float* in  = (const float*)d_in[0];
    const float* emb = (const float*)d_in[1];
    float* out = (float*)d_out;
    float* ws  = (float*)d_ws;

    vq_init<<<4, 256, 0, stream>>>(emb, ws);
    vq_main<<<N_ROWS / RPB, 512, 0, stream>>>(in, emb, out, ws);
    vq_final<<<1, 1024, 0, stream>>>(out, ws);
}